// Round 10
// baseline (194.162 us; speedup 1.0000x reference)
//
#include <hip/hip_runtime.h>
#include <hip/hip_bf16.h>
#include <stdint.h>

// Causal self-attention via MFMA, B=2 L=2048 H=16 E=D=64, fp32 I/O.
// Swapped QK^T: S^T = K·Q^T with mfma_f32_32x32x16_bf16 (A=K rows, B=Q cols).
//   C-frag: col = q = lane&31, row = kv = (reg&3) + 8*(reg>>2) + 4*(lane>>5).
// Precision: QK^T bf16 hi/lo 3-term (≈fp32); P single bf16; PV V hi/lo 2-term.
//
// R10 = R9 with exp2 via exp2f() (guaranteed builtin; v_exp_f32 IS exp2 on gfx9+).
//   pack_kv: builds the 32KB swizzled image in LDS (same conversion code as the
//     verified R6 staging), then dumps LDS->WS as coalesced 16B stores (R8's
//     direct-to-global version scattered 8B stores at 512B stride -> ~79us).
//   attn_mfma_ws: log2e folded into Q-scale (softmax in exp2 domain), exact
//     rescale-skip (__any(mt>m); fr==1 case costs nothing), s_setprio around
//     MFMA clusters (T5).
//   Grid 512 = (16 qt x 32 bh); CU-paired qt map (id,id+256) -> ~34 tiles/CU;
//   id%8 = bh%8 XCD-sticky; 2 blocks/CU; dbuf LDS, STAGE-before-compute,
//   one vmcnt-draining __syncthreads per tile.
// Fallback (ws too small): R6 monolithic kernel (passed at 226us).

#define B_ 2
#define L_ 2048
#define H_ 16
#define E_ 64

typedef short s8x  __attribute__((ext_vector_type(8)));   // 8 bf16 (4 VGPR)
typedef float f16x __attribute__((ext_vector_type(16)));  // MFMA C/D

__device__ __forceinline__ unsigned short f2bf(float f) {
    __hip_bfloat16 h = __float2bfloat16(f);   // RN
    return __builtin_bit_cast(unsigned short, h);
}
__device__ __forceinline__ float bf2f(unsigned short u) {
    __hip_bfloat16 h = __builtin_bit_cast(__hip_bfloat16, u);
    return __bfloat162float(h);
}
__device__ __forceinline__ unsigned int pk(unsigned short lo, unsigned short hi) {
    return (unsigned int)lo | ((unsigned int)hi << 16);
}
__device__ __forceinline__ void gload_lds16(const unsigned int* g, unsigned int* l) {
    auto* gp = reinterpret_cast<const __attribute__((address_space(1))) unsigned int*>(
        reinterpret_cast<uintptr_t>(g));
    auto* lp = reinterpret_cast<__attribute__((address_space(3))) unsigned int*>(
        reinterpret_cast<uintptr_t>(l));
    __builtin_amdgcn_global_load_lds(gp, lp, 16, 0, 0);
}

// ============ pack kernel: K/V -> swizzled tile images (LDS-staged dump) ============
__global__ __launch_bounds__(256)
void pack_kv(const float* __restrict__ K, const float* __restrict__ V,
             unsigned int* __restrict__ WS) {
    __shared__ unsigned int img[8192];    // 32KB image built here, dumped linearly

    const int id  = blockIdx.x;        // bh*32 + t
    const int bh  = id >> 5;
    const int t   = id & 31;
    const int b   = bh >> 4;
    const int h   = bh & 15;
    const int tid = threadIdx.x;
    const size_t bh_off = ((size_t)b * L_ * H_ + h) * E_;
    const int j0 = t * 64;
    const float* Kt = K + bh_off + (size_t)j0 * 1024;
    const float* Vt = V + bh_off + (size_t)j0 * 1024;

#pragma unroll
    for (int kk = 0; kk < 4; ++kk) {
        const int kv = kk * 16 + (tid >> 4);
        const int e4 = tid & 15;
        const float4 v = *(const float4*)(Kt + (size_t)kv * 1024 + e4 * 4);
        const unsigned short hx = f2bf(v.x), hy = f2bf(v.y),
                             hz = f2bf(v.z), hw = f2bf(v.w);
        const unsigned short lx = f2bf(v.x - bf2f(hx)), ly = f2bf(v.y - bf2f(hy)),
                             lz = f2bf(v.z - bf2f(hz)), lw = f2bf(v.w - bf2f(hw));
        const int w = (e4 * 2) ^ ((kv & 7) << 2);
        *(uint2*)&img[kv * 32 + w]        = make_uint2(pk(hx, hy), pk(hz, hw));
        *(uint2*)&img[2048 + kv * 32 + w] = make_uint2(pk(lx, ly), pk(lz, lw));
    }
    const int d4 = (tid & 15) * 4;
    const int kb = tid >> 4;
    const float4 f0 = *(const float4*)(Vt + (size_t)(kb * 4 + 0) * 1024 + d4);
    const float4 f1 = *(const float4*)(Vt + (size_t)(kb * 4 + 1) * 1024 + d4);
    const float4 f2 = *(const float4*)(Vt + (size_t)(kb * 4 + 2) * 1024 + d4);
    const float4 f3 = *(const float4*)(Vt + (size_t)(kb * 4 + 3) * 1024 + d4);
#pragma unroll
    for (int qq = 0; qq < 4; ++qq) {   // in-register 4x4 transpose
        const float e0 = ((const float*)&f0)[qq], e1 = ((const float*)&f1)[qq],
                    e2 = ((const float*)&f2)[qq], e3 = ((const float*)&f3)[qq];
        const unsigned short h0 = f2bf(e0), h1 = f2bf(e1),
                             h2 = f2bf(e2), h3 = f2bf(e3);
        const unsigned short l0 = f2bf(e0 - bf2f(h0)), l1 = f2bf(e1 - bf2f(h1)),
                             l2 = f2bf(e2 - bf2f(h2)), l3 = f2bf(e3 - bf2f(h3));
        const int d = d4 + qq;
        const int g = (((d >> 2) & 3) << 1) | (d & 1);
        const int w = (kb * 2) ^ (g << 2);
        *(uint2*)&img[4096 + d * 32 + w] = make_uint2(pk(h0, h1), pk(h2, h3));
        *(uint2*)&img[6144 + d * 32 + w] = make_uint2(pk(l0, l1), pk(l2, l3));
    }
    __syncthreads();
    // coalesced dump: 8 x (256 threads x 16B) = 32KB
    unsigned int* dst = WS + (size_t)id * 8192;
#pragma unroll
    for (int it = 0; it < 8; ++it) {
        const int o = it * 1024 + tid * 4;
        *(uint4*)&dst[o] = *(const uint4*)&img[o];
    }
}

// ===================== attention kernel (packed ws, dbuf LDS) =====================
__global__ __launch_bounds__(256, 2)
void attn_mfma_ws(const float* __restrict__ Q, const unsigned int* __restrict__ WS,
                  const float* __restrict__ scale_p, float* __restrict__ O) {
    __shared__ unsigned int lds[16384];   // 2 x 32KB tile buffers

    const int tid  = threadIdx.x;
    const int lane = tid & 63;
    const int wv   = tid >> 6;
    const int c    = lane & 31;
    const int hb   = lane >> 5;
    const int id   = blockIdx.x;
    const int bh   = id & 31;             // id%8 = bh%8 -> bh-sticky XCD
    // CU-pairing: blocks id and id+256 co-reside on a CU; qt {15-k, k} -> ~34 tiles/CU
    const int qt   = (id < 256) ? (15 - (id >> 5)) : ((id >> 5) - 8);
    const int b    = bh >> 4;
    const int h    = bh & 15;
    // fold log2e into the Q-side scale: scores live in the exp2 domain
    const float scale = *scale_p * 1.44269504088896340736f;

    const int gk = c & 7;
    const int gv = (((c >> 2) & 3) << 1) | (c & 1);
    const size_t bh_off = ((size_t)b * L_ * H_ + h) * E_;
    const char* ldsb = (const char*)lds;
    const unsigned int* imgs = WS + (size_t)bh * 32 * 8192;

    const int q0w = qt * 128 + wv * 32;
    const int qg  = q0w + c;

    // ---- Q B-frags (scale folded in, then hi/lo split) ----
    const float* Qrow = Q + bh_off + (size_t)qg * 1024;
    s8x qh[4], ql[4];
#pragma unroll
    for (int ks = 0; ks < 4; ++ks) {
        const float* qp = Qrow + ks * 16 + hb * 8;
        float4 f0 = *(const float4*)(qp);
        float4 f1 = *(const float4*)(qp + 4);
        float qv[8] = {f0.x, f0.y, f0.z, f0.w, f1.x, f1.y, f1.z, f1.w};
        union { unsigned short u[8]; s8x v; } th, tl;
#pragma unroll
        for (int e = 0; e < 8; ++e) {
            const float fs = qv[e] * scale;
            const unsigned short hh = f2bf(fs);
            th.u[e] = hh;
            tl.u[e] = f2bf(fs - bf2f(hh));
        }
        qh[ks] = th.v; ql[ks] = tl.v;
    }

    f16x sA, sB, oA, oB;
#pragma unroll
    for (int i2 = 0; i2 < 16; ++i2) { oA[i2] = 0.f; oB[i2] = 0.f; }
    float m = -1e30f, l = 0.f;

    const int nt = 2 * qt + 2;

    // stage tile 0 -> buf 0 (8 x 16B direct-to-LDS per thread = 32KB/block)
#pragma unroll
    for (int qq = 0; qq < 8; ++qq) {
        const int off = wv * 2048 + qq * 256 + lane * 4;   // dwords
        gload_lds16(imgs + off, &lds[off]);
    }
    __syncthreads();   // drains vmcnt -> tile 0 resident

    for (int t = 0; t < nt; ++t) {
        // ---- issue next tile's loads into the other buffer (hidden under compute) ----
        if (t + 1 < nt) {
            const unsigned int* img = imgs + (size_t)(t + 1) * 8192;
            unsigned int* db = &lds[((t + 1) & 1) * 8192];
#pragma unroll
            for (int qq = 0; qq < 8; ++qq) {
                const int off = wv * 2048 + qq * 256 + lane * 4;
                gload_lds16(img + off, db + off);
            }
        }
        const int j0 = t * 64;
        const int bb = (t & 1) * 32768;   // current buffer byte base

        if (j0 <= q0w + 31) {   // wave-uniform skip of fully-masked tiles
            // ================= QK^T (hi*hi + hi*lo + lo*hi) =================
#pragma unroll
            for (int i2 = 0; i2 < 16; ++i2) { sA[i2] = 0.f; sB[i2] = 0.f; }
            __builtin_amdgcn_s_setprio(1);
#pragma unroll
            for (int ks = 0; ks < 4; ++ks) {
                const int wq = ((ks * 8 + hb * 4) ^ (gk << 2)) * 4;
                const s8x kAh = *(const s8x*)(ldsb + bb + c * 128 + wq);
                const s8x kAl = *(const s8x*)(ldsb + bb + 8192 + c * 128 + wq);
                const s8x kBh = *(const s8x*)(ldsb + bb + (32 + c) * 128 + wq);
                const s8x kBl = *(const s8x*)(ldsb + bb + 8192 + (32 + c) * 128 + wq);
                sA = __builtin_amdgcn_mfma_f32_32x32x16_bf16(kAh, qh[ks], sA, 0, 0, 0);
                sA = __builtin_amdgcn_mfma_f32_32x32x16_bf16(kAh, ql[ks], sA, 0, 0, 0);
                sA = __builtin_amdgcn_mfma_f32_32x32x16_bf16(kAl, qh[ks], sA, 0, 0, 0);
                sB = __builtin_amdgcn_mfma_f32_32x32x16_bf16(kBh, qh[ks], sB, 0, 0, 0);
                sB = __builtin_amdgcn_mfma_f32_32x32x16_bf16(kBh, ql[ks], sB, 0, 0, 0);
                sB = __builtin_amdgcn_mfma_f32_32x32x16_bf16(kBl, qh[ks], sB, 0, 0, 0);
            }
            __builtin_amdgcn_s_setprio(0);
            // ---- causal mask (only near-diagonal tiles branch in) ----
            if (j0 + 63 > q0w) {
#pragma unroll
                for (int i2 = 0; i2 < 16; ++i2) {
                    const int kvl = (i2 & 3) + 8 * (i2 >> 2) + 4 * hb;
                    sA[i2] = (j0 + kvl > qg)      ? -1e30f : sA[i2];
                    sB[i2] = (j0 + 32 + kvl > qg) ? -1e30f : sB[i2];
                }
            }
            // ---- online softmax in exp2 domain (row = q = lane col; partner lane^32) ----
            float mt = -1e30f;
#pragma unroll
            for (int i2 = 0; i2 < 16; ++i2) { mt = fmaxf(mt, sA[i2]); mt = fmaxf(mt, sB[i2]); }
            mt = fmaxf(mt, __shfl_xor(mt, 32, 64));
            if (__any(mt > m)) {          // exact skip: fr==1 when max didn't grow
                const float mn = fmaxf(m, mt);
                const float fr = exp2f(m - mn);
                m = mn;
                l *= fr;
#pragma unroll
                for (int i2 = 0; i2 < 16; ++i2) { oA[i2] *= fr; oB[i2] *= fr; }
            }
            float lt = 0.f;
#pragma unroll
            for (int i2 = 0; i2 < 16; ++i2) {
                const float pA = exp2f(sA[i2] - m);
                const float pB = exp2f(sB[i2] - m);
                sA[i2] = pA; sB[i2] = pB;
                lt += pA + pB;
            }
            lt += __shfl_xor(lt, 32, 64);
            l += lt;
            // ---- pack P -> bf16 words W[Mt*8 + s*2 + h] = kv {32Mt+8s+4hb+2h, +1} ----
            unsigned int W[16];
#pragma unroll
            for (int ss = 0; ss < 4; ++ss)
#pragma unroll
            for (int hh2 = 0; hh2 < 2; ++hh2) {
                const int r0 = 4 * ss + 2 * hh2;
                W[ss * 2 + hh2]     = pk(f2bf(sA[r0]), f2bf(sA[r0 + 1]));
                W[8 + ss * 2 + hh2] = pk(f2bf(sB[r0]), f2bf(sB[r0 + 1]));
            }
            // ================= PV: O^T += V^T · P^T (V hi/lo) =================
            // Lane needs kv run [ks*16+hb*8, +8): keep my W[s'=sa+hb], SEND my
            // W[sa+1-hb] (partner's slot) through shfl_xor(32).
#pragma unroll
            for (int ks = 0; ks < 4; ++ks) {
                const int Mt = ks >> 1;
                const int sa = (ks & 1) * 2;
                const unsigned int keep0 = hb ? W[Mt * 8 + (sa + 1) * 2 + 0]
                                              : W[Mt * 8 + sa * 2 + 0];
                const unsigned int keep1 = hb ? W[Mt * 8 + (sa + 1) * 2 + 1]
                                              : W[Mt * 8 + sa * 2 + 1];
                const unsigned int send0 = hb ? W[Mt * 8 + sa * 2 + 0]
                                              : W[Mt * 8 + (sa + 1) * 2 + 0];
                const unsigned int send1 = hb ? W[Mt * 8 + sa * 2 + 1]
                                              : W[Mt * 8 + (sa + 1) * 2 + 1];
                const unsigned int swp0 = (unsigned int)__shfl_xor((int)send0, 32, 64);
                const unsigned int swp1 = (unsigned int)__shfl_xor((int)send1, 32, 64);
                union { unsigned int u[4]; s8x v; } pf;
                pf.u[0] = hb ? swp0 : keep0;
                pf.u[1] = hb ? swp1 : keep1;
                pf.u[2] = hb ? keep0 : swp0;
                pf.u[3] = hb ? keep1 : swp1;
                const int wvv = ((ks * 8 + hb * 4) ^ (gv << 2)) * 4;
                const s8x vAh = *(const s8x*)(ldsb + bb + 16384 + c * 128 + wvv);
                const s8x vAl = *(const s8x*)(ldsb + bb + 24576 + c * 128 + wvv);
                const s8x vBh = *(const s8x*)(ldsb + bb + 16384 + (32 + c) * 128 + wvv);
                const s8x vBl = *(const s8x*)(ldsb + bb + 24576 + (32 + c) * 128 + wvv);
                __builtin_amdgcn_s_setprio(1);
                oA = __builtin_amdgcn_mfma_f32_32x32x16_bf16(vAh, pf.v, oA, 0, 0, 0);
                oA = __builtin_amdgcn_mfma_f32_32x32x16_bf16(vAl, pf.v, oA, 0, 0, 0);
                oB = __builtin_amdgcn_mfma_f32_32x32x16_bf16(vBh, pf.v, oB, 0, 0, 0);
                oB = __builtin_amdgcn_mfma_f32_32x32x16_bf16(vBl, pf.v, oB, 0, 0, 0);
                __builtin_amdgcn_s_setprio(0);
            }
        }
        __syncthreads();   // drains vmcnt (next tile landed) + protects buffers
    }
    // ================= epilogue: O[q][d] = o/l =================
    const float inv = 1.0f / l;
    float* Orow = O + bh_off + (size_t)qg * 1024;
#pragma unroll
    for (int i2 = 0; i2 < 16; ++i2) {
        const int d = (i2 & 3) + 8 * (i2 >> 2) + 4 * hb;
        Orow[d]      = oA[i2] * inv;
        Orow[32 + d] = oB[i2] * inv;
    }
}

// ===================== fallback: R6 monolithic kernel (passed, 226us) =====================
__global__ __launch_bounds__(256, 1)
void attn_mfma_fb(const float* __restrict__ Q, const float* __restrict__ K,
                  const float* __restrict__ V, const float* __restrict__ scale_p,
                  float* __restrict__ O) {
    __shared__ unsigned int lds[8192];
    const int tid  = threadIdx.x;
    const int lane = tid & 63;
    const int wv   = tid >> 6;
    const int c    = lane & 31;
    const int hb   = lane >> 5;
    const int bh   = blockIdx.x & 31;
    const int jj   = blockIdx.x >> 5;
    const int b    = bh >> 4;
    const int h    = bh & 15;
    const float scale = *scale_p;
    const int gk = c & 7;
    const int gv = (((c >> 2) & 3) << 1) | (c & 1);
    const size_t bh_off = ((size_t)b * L_ * H_ + h) * E_;
    const char* ldsb = (const char*)lds;

    for (int ci = 0; ci < 2; ++ci) {
        const int qt  = ci ? (15 - jj) : jj;
        const int q0w = qt * 128 + wv * 32;
        const int qg  = q0w + c;
        const float* Qrow = Q + bh_off + (size_t)qg * 1024;
        s8x qh[4], ql[4];
#pragma unroll
        for (int ks = 0; ks < 4; ++ks) {
            const float* qp = Qrow + ks * 16 + hb * 8;
            float4 f0 = *(const float4*)(qp);
            float4 f1 = *(const float4*)(qp + 4);
            float qv[8] = {f0.x, f0.y, f0.z, f0.w, f1.x, f1.y, f1.z, f1.w};
            union { unsigned short u[8]; s8x v; } th, tl;
#pragma unroll
            for (int e = 0; e < 8; ++e) {
                const float fs = qv[e] * scale;
                const unsigned short hh = f2bf(fs);
                th.u[e] = hh;
                tl.u[e] = f2bf(fs - bf2f(hh));
            }
            qh[ks] = th.v; ql[ks] = tl.v;
        }
        f16x sA, sB, oA, oB;
#pragma unroll
        for (int i2 = 0; i2 < 16; ++i2) { oA[i2] = 0.f; oB[i2] = 0.f; }
        float m = -1e30f, l = 0.f;
        const int nt = 2 * qt + 2;
        for (int t = 0; t < nt; ++t) {
            const int j0 = t * 64;
            {
                const float* Kt = K + bh_off + (size_t)j0 * 1024;
                const float* Vt = V + bh_off + (size_t)j0 * 1024;
#pragma unroll
                for (int kk = 0; kk < 4; ++kk) {
                    const int kv = kk * 16 + (tid >> 4);
                    const int e4 = tid & 15;
                    const float4 v = *(const float4*)(Kt + (size_t)kv * 1024 + e4 * 4);
                    const unsigned short hx = f2bf(v.x), hy = f2bf(v.y),
                                         hz = f2bf(v.z), hw = f2bf(v.w);
                    const unsigned short lx = f2bf(v.x - bf2f(hx)), ly = f2bf(v.y - bf2f(hy)),
                                         lz = f2bf(v.z - bf2f(hz)), lw = f2bf(v.w - bf2f(hw));
                    const int w = (e4 * 2) ^ ((kv & 7) << 2);
                    *(uint2*)&lds[kv * 32 + w]        = make_uint2(pk(hx, hy), pk(hz, hw));
                    *(uint2*)&lds[2048 + kv * 32 + w] = make_uint2(pk(lx, ly), pk(lz, lw));
                }
                const int d4 = (tid & 15) * 4;
                const int kb = tid >> 4;
                const float4 f0 = *(const float4*)(Vt + (size_t)(kb * 4 + 0) * 1024 + d4);
                const float4 f1 = *(const float4*)(Vt + (size_t)(kb * 4 + 1) * 1024 + d4);
                const float4 f2 = *(const float4*)(Vt + (size_t)(kb * 4 + 2) * 1024 + d4);
                const float4 f3 = *(const float4*)(Vt + (size_t)(kb * 4 + 3) * 1024 + d4);
#pragma unroll
                for (int qq = 0; qq < 4; ++qq) {
                    const float e0 = ((const float*)&f0)[qq], e1 = ((const float*)&f1)[qq],
                                e2 = ((const float*)&f2)[qq], e3 = ((const float*)&f3)[qq];
                    const unsigned short h0 = f2bf(e0), h1 = f2bf(e1),
                                         h2 = f2bf(e2), h3 = f2bf(e3);
                    const unsigned short l0 = f2bf(e0 - bf2f(h0)), l1 = f2bf(e1 - bf2f(h1)),
                                         l2 = f2bf(e2 - bf2f(h2)), l3 = f2bf(e3 - bf2f(h3));
                    const int d = d4 + qq;
                    const int g = (((d >> 2) & 3) << 1) | (d & 1);
                    const int w = (kb * 2) ^ (g << 2);
                    *(uint2*)&lds[4096 + d * 32 + w] = make_uint2(pk(h0, h1), pk(h2, h3));
                    *(uint2*)&lds[6144 + d * 32 + w] = make_uint2(pk(l0, l1), pk(l2, l3));
                }
            }
            __syncthreads();
            if (j0 <= q0w + 31) {
#pragma unroll
                for (int i2 = 0; i2 < 16; ++i2) { sA[i2] = 0.f; sB[i2] = 0.f; }
#pragma unroll
                for (int ks = 0; ks < 4; ++ks) {
                    const int wq = ((ks * 8 + hb * 4) ^ (gk << 2)) * 4;
                    const s8x kAh = *(const s8x*)(ldsb + c * 128 + wq);
                    const s8x kAl = *(const s8x*)(ldsb + 8192 + c * 128 + wq);
                    const s8x kBh = *(const s8x*)(ldsb + (32 + c) * 128 + wq);
                    const s8x kBl = *(const s8x*)(ldsb + 8192 + (32 + c) * 128 + wq);
                    sA = __builtin_amdgcn_mfma_f32_32x32x16_bf16(kAh, qh[ks], sA, 0, 0, 0);
                    sA = __builtin_amdgcn_mfma_f32_32x32x16_bf16(kAh, ql[ks], sA, 0, 0, 0);
                    sA = __builtin_amdgcn_mfma_f32_32x32x16_bf16(kAl, qh[ks], sA, 0, 0, 0);
                    sB = __builtin_amdgcn_mfma_f32_32x32x16_bf16(kBh, qh[ks], sB, 0, 0, 0);
                    sB = __builtin_amdgcn_mfma_f32_32x32x16_bf16(kBh, ql[ks], sB, 0, 0, 0);
                    sB = __builtin_amdgcn_mfma_f32_32x32x16_bf16(kBl, qh[ks], sB, 0, 0, 0);
                }
                if (j0 + 63 > q0w) {
#pragma unroll
                    for (int i2 = 0; i2 < 16; ++i2) {
                        const int kvl = (i2 & 3) + 8 * (i2 >> 2) + 4 * hb;
                        sA[i2] = (j0 + kvl > qg)      ? -1e30f : sA[i2];
                        sB[i2] = (j0 + 32 + kvl > qg) ? -1e30f : sB[i2];
                    }
                }
                float mt = -1e30f;
#pragma unroll
                for (int i2 = 0; i2 < 16; ++i2) { mt = fmaxf(mt, sA[i2]); mt = fmaxf(mt, sB[i2]); }
                mt = fmaxf(mt, __shfl_xor(mt, 32, 64));
                const float mn = fmaxf(m, mt);
                const float fr = __expf(m - mn);
                m = mn;
                l *= fr;
#pragma unroll
                for (int i2 = 0; i2 < 16; ++i2) { oA[i2] *= fr; oB[i2] *= fr; }
                float lt = 0.f;
#pragma unroll
                for (int i2 = 0; i2 < 16; ++i2) {
                    const float pA = __expf(sA[i2] - m);
                    const float pB = __expf(sB[i2] - m);
                    sA[i2] = pA; sB[i2] = pB;
                    lt += pA + pB;
                }
                lt += __shfl_xor(lt, 32, 64);
                l += lt;
                unsigned int W[16];
#pragma unroll
                for (int ss = 0; ss < 4; ++ss)
#pragma unroll
                for (int hh2 = 0; hh2 < 2; ++hh2) {
                    const int r0 = 4 * ss + 2 * hh2;
                    W[ss * 2 + hh2]     = pk(f2bf(sA[r0]), f2bf(sA[r0 + 1]));
                    W[8 + ss * 2 + hh2] = pk(f2bf(sB[r0]), f2bf(sB[r0 + 1]));
                }
#pragma unroll
                for (int ks = 0; ks < 4; ++ks) {
                    const int Mt = ks >> 1;
                    const int sa = (ks & 1) * 2;
                    const unsigned int keep0 = hb ? W[Mt * 8 + (sa + 1) * 2 + 0]
                                                  : W[Mt * 8 + sa * 2 + 0];
                    const unsigned int keep1 = hb ? W[Mt * 8 + (sa + 1) * 2 + 1]
                                                  : W[Mt * 8 + sa * 2 + 1];
                    const unsigned int send0 = hb ? W[Mt * 8 + sa * 2 + 0]
                                                  : W[Mt * 8 + (sa + 1) * 2 + 0];
                    const unsigned int send1 = hb ? W[Mt * 8 + sa * 2 + 1]
                                                  : W[Mt * 8 + (sa + 1) * 2 + 1];
                    const unsigned int swp0 = (unsigned int)__shfl_xor((int)send0, 32, 64);
                    const unsigned int swp1 = (unsigned int)__shfl_xor((int)send1, 32, 64);
                    union { unsigned int u[4]; s8x v; } pf;
                    pf.u[0] = hb ? swp0 : keep0;
                    pf.u[1] = hb ? swp1 : keep1;
                    pf.u[2] = hb ? keep0 : swp0;
                    pf.u[3] = hb ? keep1 : swp1;
                    const int wvv = ((ks * 8 + hb * 4) ^ (gv << 2)) * 4;
                    const s8x vAh = *(const s8x*)(ldsb + 16384 + c * 128 + wvv);
                    const s8x vAl = *(const s8x*)(ldsb + 24576 + c * 128 + wvv);
                    const s8x vBh = *(const s8x*)(ldsb + 16384 + (32 + c) * 128 + wvv);
                    const s8x vBl = *(const s8x*)(ldsb + 24576 + (32 + c) * 128 + wvv);
                    oA = __builtin_amdgcn_mfma_f32_32x32x16_bf16(vAh, pf.v, oA, 0, 0, 0);
                    oA = __builtin_amdgcn_mfma_f32_32x32x16_bf16(vAl, pf.v, oA, 0, 0, 0);
                    oB = __builtin_amdgcn_mfma_f32_32x32x16_bf16(vBh, pf.v, oB, 0, 0, 0);
                    oB = __builtin_amdgcn_mfma_f32_32x32x16_bf16(vBl, pf.v, oB, 0, 0, 0);
                }
            }
            __syncthreads();
        }
        const float inv = 1.0f / l;
        float* Orow = O + bh_off + (size_t)qg * 1024;
#pragma unroll
        for (int i2 = 0; i2 < 16; ++i2) {
            const int d = (i2 & 3) + 8 * (i2 >> 2) + 4 * hb;
            Orow[d]      = oA[i2] * inv;
            Orow[32 + d] = oB[i2] * inv;
        }
    }
}

extern "C" void kernel_launch(void* const* d_in, const int* in_sizes, int n_in,
                              void* d_out, int out_size, void* d_ws, size_t ws_size,
                              hipStream_t stream) {
    const float* Q = (const float*)d_in[0];
    const float* K = (const float*)d_in[1];
    const float* V = (const float*)d_in[2];
    const float* scale = (const float*)d_in[3];
    float* O = (float*)d_out;

    const size_t need = (size_t)32 * 32 * 32768;   // 32 bh x 32 tiles x 32KB = 33.5MB
    if (ws_size >= need) {
        unsigned int* WS = (unsigned int*)d_ws;
        pack_kv<<<dim3(1024), 256, 0, stream>>>(K, V, WS);
        attn_mfma_ws<<<dim3(512), 256, 0, stream>>>(Q, WS, scale, O);
    } else {
        attn_mfma_fb<<<dim3(256), 256, 0, stream>>>(Q, K, V, scale, O);
    }
}